// Round 1
// baseline (426.181 us; speedup 1.0000x reference)
//
#include <hip/hip_runtime.h>
#include <math.h>

#define B 32
#define NTOK 16384
#define DIM 64
#define NS 8
#define HID 128
#define BPB 32                  // blocks per batch for flash pass
#define JPB (NTOK/BPB)          // 512 tokens per block
#define NWAVE 4
#define JPW (JPB/NWAVE)         // 128 tokens per wave
#define PARTF (8+8+64+512)      // m[8], l[8], xsum[64], acc[8*64] = 592 floats
#define NPART (B*BPB*NWAVE)     // 4096 wave-partials
#define SCALE 0.125f
#define EPSA 1e-8f
#define LNEPS 1e-5f
#define SUMATTN (1.0f + (float)NTOK*EPSA)

// ---------------------------------------------------------------------------
// Flash pass: one streaming sweep over inputs. Computes (per block, redundantly)
// q' = (LN(slots)@Wq^T+bq)@Wk * SCALE so dots_ij = q'_i . LN(x_j) + c_i.
// Online softmax per slot; accumulates acc_i[d] = sum_j e^{s_ij-m_i} xln_j[d]
// and xsum[d] = sum_j xln_j[d]. Writes one 592-float partial per wave.
// If store_dots, writes raw dots into d_out's attn region.
// Lane mapping: lane = jsub*8 + dgrp; each lane handles 8 dims of one token.
// ---------------------------------------------------------------------------
__global__ __launch_bounds__(256) void k_flash(
    const float* __restrict__ x, const float* __restrict__ slots,
    const float* __restrict__ ln_in_g, const float* __restrict__ ln_in_b,
    const float* __restrict__ ln_s_g, const float* __restrict__ ln_s_b,
    const float* __restrict__ Wq, const float* __restrict__ bq,
    const float* __restrict__ Wk, const float* __restrict__ bk,
    float* __restrict__ partials, float* __restrict__ dots_out, int store_dots)
{
  __shared__ float sS[NS][DIM];
  __shared__ float sQ[NS][DIM];
  __shared__ float sQp[NS][DIM];
  __shared__ float sC[NS];
  const int b = blockIdx.x / BPB, blk = blockIdx.x % BPB;
  const int t = threadIdx.x;

  // --- tiny per-block preamble: LN(slots), q, q' ---
  if (t < NS) {
    const float* sr = slots + ((size_t)b*NS + t)*DIM;
    float s1 = 0.f, s2 = 0.f;
    for (int d = 0; d < DIM; ++d) { float v = sr[d]; s1 += v; s2 += v*v; }
    float mu = s1*(1.0f/DIM);
    float var = s2*(1.0f/DIM) - mu*mu;
    float rs = rsqrtf(var + LNEPS);
    for (int d = 0; d < DIM; ++d) sS[t][d] = (sr[d]-mu)*rs*ln_s_g[d] + ln_s_b[d];
  }
  __syncthreads();
  for (int o = t; o < NS*DIM; o += 256) {
    int i = o >> 6, e = o & 63;
    float a = bq[e];
    const float* wr = Wq + e*DIM;
    for (int d = 0; d < DIM; ++d) a = fmaf(sS[i][d], wr[d], a);
    sQ[i][e] = a;
  }
  __syncthreads();
  for (int o = t; o < NS*DIM; o += 256) {
    int i = o >> 6, d = o & 63;
    float a = 0.f;
    for (int e = 0; e < DIM; ++e) a = fmaf(sQ[i][e], Wk[e*DIM + d], a);
    sQp[i][d] = a * SCALE;
  }
  if (t < NS) {
    float a = 0.f;
    for (int e = 0; e < DIM; ++e) a = fmaf(sQ[t][e], bk[e], a);
    sC[t] = a * SCALE;
  }
  __syncthreads();

  const int lane = t & 63, w = t >> 6;
  const int jsub = lane >> 3, dgrp = lane & 7;
  const int j0 = blk*JPB + w*JPW;

  float qp[NS][8], c[NS];
  #pragma unroll
  for (int i = 0; i < NS; ++i) {
    c[i] = sC[i];
    #pragma unroll
    for (int dd = 0; dd < 8; ++dd) qp[i][dd] = sQp[i][dgrp*8 + dd];
  }
  float g[8], bl[8];
  #pragma unroll
  for (int dd = 0; dd < 8; ++dd) {
    g[dd]  = ln_in_g[dgrp*8 + dd];
    bl[dd] = ln_in_b[dgrp*8 + dd];
  }

  float m[NS], l[NS], acc[NS][8], xs[8];
  #pragma unroll
  for (int i = 0; i < NS; ++i) {
    m[i] = -INFINITY; l[i] = 0.f;
    #pragma unroll
    for (int dd = 0; dd < 8; ++dd) acc[i][dd] = 0.f;
  }
  #pragma unroll
  for (int dd = 0; dd < 8; ++dd) xs[dd] = 0.f;

  const float* xb = x + (size_t)b*NTOK*DIM;
  // prefetch first token chunk
  const float4* xr = (const float4*)(xb + (size_t)(j0 + jsub)*DIM + dgrp*8);
  float4 a0 = xr[0], a1 = xr[1];

  for (int it = 0; it < JPW/8; ++it) {
    int j = j0 + it*8 + jsub;
    float4 n0, n1;
    if (it + 1 < JPW/8) {
      const float4* nx = (const float4*)(xb + (size_t)(j + 8)*DIM + dgrp*8);
      n0 = nx[0]; n1 = nx[1];
    }
    float xv[8] = {a0.x,a0.y,a0.z,a0.w,a1.x,a1.y,a1.z,a1.w};
    float s1 = 0.f, s2 = 0.f;
    #pragma unroll
    for (int dd = 0; dd < 8; ++dd) { s1 += xv[dd]; s2 = fmaf(xv[dd], xv[dd], s2); }
    s1 += __shfl_xor(s1, 1); s2 += __shfl_xor(s2, 1);
    s1 += __shfl_xor(s1, 2); s2 += __shfl_xor(s2, 2);
    s1 += __shfl_xor(s1, 4); s2 += __shfl_xor(s2, 4);
    float mu = s1*(1.0f/DIM);
    float var = s2*(1.0f/DIM) - mu*mu;
    float rs = rsqrtf(var + LNEPS);
    float xln[8];
    #pragma unroll
    for (int dd = 0; dd < 8; ++dd) {
      xln[dd] = (xv[dd]-mu)*rs*g[dd] + bl[dd];
      xs[dd] += xln[dd];
    }
    float sd[NS];
    #pragma unroll
    for (int i = 0; i < NS; ++i) {
      float a = 0.f;
      #pragma unroll
      for (int dd = 0; dd < 8; ++dd) a = fmaf(qp[i][dd], xln[dd], a);
      a += __shfl_xor(a, 1); a += __shfl_xor(a, 2); a += __shfl_xor(a, 4);
      sd[i] = a + c[i];
    }
    if (store_dots) {
      float outv = sd[0];
      #pragma unroll
      for (int i = 1; i < NS; ++i) outv = (dgrp == i) ? sd[i] : outv;
      dots_out[((size_t)b*NS + dgrp)*NTOK + j] = outv;
    }
    #pragma unroll
    for (int i = 0; i < NS; ++i) {
      float nm = fmaxf(m[i], sd[i]);
      float sc = __expf(m[i] - nm);
      float p  = __expf(sd[i] - nm);
      l[i] = fmaf(l[i], sc, p);
      m[i] = nm;
      #pragma unroll
      for (int dd = 0; dd < 8; ++dd) acc[i][dd] = fmaf(acc[i][dd], sc, p*xln[dd]);
    }
    a0 = n0; a1 = n1;
  }

  // merge across jsub groups (lanes differing in bits 3,4,5)
  #pragma unroll
  for (int stepi = 0; stepi < 3; ++stepi) {
    const int mask = 8 << stepi;
    #pragma unroll
    for (int i = 0; i < NS; ++i) {
      float om = __shfl_xor(m[i], mask);
      float ol = __shfl_xor(l[i], mask);
      float nm = fmaxf(m[i], om);
      float s1 = __expf(m[i] - nm);
      float s2 = __expf(om - nm);
      l[i] = l[i]*s1 + ol*s2;
      #pragma unroll
      for (int dd = 0; dd < 8; ++dd) {
        float oa = __shfl_xor(acc[i][dd], mask);
        acc[i][dd] = acc[i][dd]*s1 + oa*s2;
      }
      m[i] = nm;
    }
    #pragma unroll
    for (int dd = 0; dd < 8; ++dd) xs[dd] += __shfl_xor(xs[dd], mask);
  }

  float* P = partials + ((size_t)(b*BPB + blk)*NWAVE + w)*PARTF;
  if (lane == 0) {
    #pragma unroll
    for (int i = 0; i < NS; ++i) { P[i] = m[i]; P[8+i] = l[i]; }
  }
  if (jsub == 0) {
    #pragma unroll
    for (int dd = 0; dd < 8; ++dd) P[16 + dgrp*8 + dd] = xs[dd];
    #pragma unroll
    for (int i = 0; i < NS; ++i) {
      #pragma unroll
      for (int dd = 0; dd < 8; ++dd) P[80 + i*64 + dgrp*8 + dd] = acc[i][dd];
    }
  }
}

// ---------------------------------------------------------------------------
// Per-batch combine + slot update: merge 128 wave-partials -> updates,
// then GRUCell + residual MLP -> new slots. Optionally store m/1/l for norm.
// ---------------------------------------------------------------------------
__global__ __launch_bounds__(256) void k_update(
    const float* __restrict__ partials, const float* __restrict__ prev,
    const float* __restrict__ ln_ff_g, const float* __restrict__ ln_ff_b,
    const float* __restrict__ Wv, const float* __restrict__ bv,
    const float* __restrict__ W_ih, const float* __restrict__ b_ih,
    const float* __restrict__ W_hh, const float* __restrict__ b_hh,
    const float* __restrict__ W1, const float* __restrict__ b1,
    const float* __restrict__ W2, const float* __restrict__ b2,
    float* __restrict__ slots_out, int store_ml,
    float* __restrict__ mfin, float* __restrict__ linv)
{
  __shared__ float sM[NS], sL[NS], sXsum[DIM];
  __shared__ float sScale[BPB*NWAVE][NS];
  __shared__ float sUX[NS][DIM];
  __shared__ float sUpd[NS][DIM];
  __shared__ float sGx[NS][3*DIM], sGh[NS][3*DIM];
  __shared__ float sH[NS][DIM], sHln[NS][DIM];
  __shared__ float sPrev[NS][DIM];
  __shared__ float sMu[NS], sRs[NS];
  __shared__ float sM1[NS][HID];

  const int b = blockIdx.x, t = threadIdx.x;
  const int NP = BPB*NWAVE;
  const float* Pb = partials + (size_t)b*NP*PARTF;

  for (int o = t; o < NS*DIM; o += 256) ((float*)sPrev)[o] = prev[(size_t)b*NS*DIM + o];
  if (t < NS) {
    float mm = -INFINITY;
    for (int p = 0; p < NP; ++p) mm = fmaxf(mm, Pb[p*PARTF + t]);
    float ll = 0.f;
    for (int p = 0; p < NP; ++p) ll += Pb[p*PARTF + 8 + t]*__expf(Pb[p*PARTF + t] - mm);
    sM[t] = mm; sL[t] = ll;
  }
  if (t >= 64 && t < 128) {
    int d = t - 64;
    float a = 0.f;
    for (int p = 0; p < NP; ++p) a += Pb[p*PARTF + 16 + d];
    sXsum[d] = a;
  }
  __syncthreads();
  for (int o = t; o < NP*NS; o += 256) {
    int p = o >> 3, i = o & 7;
    sScale[p][i] = __expf(Pb[p*PARTF + i] - sM[i]);
  }
  __syncthreads();
  for (int o = t; o < NS*DIM; o += 256) {
    int i = o >> 6, d = o & 63;
    float a = 0.f;
    for (int p = 0; p < NP; ++p) a = fmaf(Pb[p*PARTF + 80 + o], sScale[p][i], a);
    sUX[i][d] = a/sL[i] + EPSA*sXsum[d];
  }
  __syncthreads();
  for (int o = t; o < NS*DIM; o += 256) {
    int i = o >> 6, e = o & 63;
    float a = bv[e]*SUMATTN;
    const float* wr = Wv + e*DIM;
    for (int d = 0; d < DIM; ++d) a = fmaf(sUX[i][d], wr[d], a);
    sUpd[i][e] = a;
  }
  __syncthreads();
  for (int o = t; o < NS*3*DIM; o += 256) {
    int i = o/(3*DIM), oo = o%(3*DIM);
    float ax = b_ih[oo], ah = b_hh[oo];
    const float* wx = W_ih + oo*DIM;
    const float* wh = W_hh + oo*DIM;
    for (int e = 0; e < DIM; ++e) {
      ax = fmaf(sUpd[i][e], wx[e], ax);
      ah = fmaf(sPrev[i][e], wh[e], ah);
    }
    sGx[i][oo] = ax; sGh[i][oo] = ah;
  }
  __syncthreads();
  for (int o = t; o < NS*DIM; o += 256) {
    int i = o >> 6, e = o & 63;
    float r = 1.0f/(1.0f + __expf(-(sGx[i][e] + sGh[i][e])));
    float z = 1.0f/(1.0f + __expf(-(sGx[i][DIM+e] + sGh[i][DIM+e])));
    float n = tanhf(sGx[i][2*DIM+e] + r*sGh[i][2*DIM+e]);
    sH[i][e] = (1.0f - z)*n + z*sPrev[i][e];
  }
  __syncthreads();
  if (t < NS) {
    float s1 = 0.f, s2 = 0.f;
    for (int d = 0; d < DIM; ++d) { float v = sH[t][d]; s1 += v; s2 += v*v; }
    float mu = s1*(1.0f/DIM);
    float var = s2*(1.0f/DIM) - mu*mu;
    sMu[t] = mu; sRs[t] = rsqrtf(var + LNEPS);
  }
  __syncthreads();
  for (int o = t; o < NS*DIM; o += 256) {
    int i = o >> 6, d = o & 63;
    sHln[i][d] = (sH[i][d]-sMu[i])*sRs[i]*ln_ff_g[d] + ln_ff_b[d];
  }
  __syncthreads();
  for (int o = t; o < NS*HID; o += 256) {
    int i = o >> 7, h = o & 127;
    float a = b1[h];
    const float* wr = W1 + h*DIM;
    for (int d = 0; d < DIM; ++d) a = fmaf(sHln[i][d], wr[d], a);
    sM1[i][h] = fmaxf(a, 0.0f);
  }
  __syncthreads();
  for (int o = t; o < NS*DIM; o += 256) {
    int i = o >> 6, e = o & 63;
    float a = b2[e];
    const float* wr = W2 + e*HID;
    for (int h = 0; h < HID; ++h) a = fmaf(sM1[i][h], wr[h], a);
    slots_out[(size_t)b*NS*DIM + o] = sH[i][e] + a;
  }
  if (store_ml && t < NS) {
    mfin[b*NS + t] = sM[t];
    linv[b*NS + t] = 1.0f/sL[t];
  }
}

// ---------------------------------------------------------------------------
// Normalize raw dots (stored in d_out attn region) in place:
// attn = exp(dots - m)/l + EPS
// ---------------------------------------------------------------------------
__global__ __launch_bounds__(256) void k_norm(
    float* __restrict__ dout, const float* __restrict__ mfin,
    const float* __restrict__ linv)
{
  const size_t total4 = (size_t)B*NS*NTOK/4;
  size_t idx = (size_t)blockIdx.x*256 + threadIdx.x;
  size_t stride = (size_t)gridDim.x*256;
  for (size_t q = idx; q < total4; q += stride) {
    float4* p = ((float4*)dout) + q;
    float4 v = *p;
    int bi = (int)(q >> 12);   // 4096 float4 per (b,slot) row
    float mm = mfin[bi], li = linv[bi];
    v.x = __expf(v.x - mm)*li + EPSA;
    v.y = __expf(v.y - mm)*li + EPSA;
    v.z = __expf(v.z - mm)*li + EPSA;
    v.w = __expf(v.w - mm)*li + EPSA;
    *p = v;
  }
}

extern "C" void kernel_launch(void* const* d_in, const int* in_sizes, int n_in,
                              void* d_out, int out_size, void* d_ws, size_t ws_size,
                              hipStream_t stream)
{
  const float* x       = (const float*)d_in[0];
  const float* slots0  = (const float*)d_in[1];
  const float* ln_in_g = (const float*)d_in[2];
  const float* ln_in_b = (const float*)d_in[3];
  const float* ln_s_g  = (const float*)d_in[4];
  const float* ln_s_b  = (const float*)d_in[5];
  const float* ln_ff_g = (const float*)d_in[6];
  const float* ln_ff_b = (const float*)d_in[7];
  const float* Wq = (const float*)d_in[8];
  const float* bq = (const float*)d_in[9];
  const float* Wk = (const float*)d_in[10];
  const float* bk = (const float*)d_in[11];
  const float* Wv = (const float*)d_in[12];
  const float* bv = (const float*)d_in[13];
  const float* W_ih = (const float*)d_in[14];
  const float* b_ih = (const float*)d_in[15];
  const float* W_hh = (const float*)d_in[16];
  const float* b_hh = (const float*)d_in[17];
  const float* W1 = (const float*)d_in[18];
  const float* b1 = (const float*)d_in[19];
  const float* W2 = (const float*)d_in[20];
  const float* b2 = (const float*)d_in[21];

  float* out = (float*)d_out;
  float* partials = (float*)d_ws;
  float* sA   = partials + (size_t)NPART*PARTF;
  float* sB   = sA + (size_t)B*NS*DIM;
  float* mfin = sB + (size_t)B*NS*DIM;
  float* linv = mfin + B*NS;
  float* outslots = out + (size_t)B*NS*NTOK;

  dim3 gridF(B*BPB), blk(256);

  // iteration 0
  k_flash<<<gridF, blk, 0, stream>>>(x, slots0, ln_in_g, ln_in_b, ln_s_g, ln_s_b,
                                     Wq, bq, Wk, bk, partials, nullptr, 0);
  k_update<<<B, blk, 0, stream>>>(partials, slots0, ln_ff_g, ln_ff_b, Wv, bv,
                                  W_ih, b_ih, W_hh, b_hh, W1, b1, W2, b2,
                                  sA, 0, mfin, linv);
  // iteration 1
  k_flash<<<gridF, blk, 0, stream>>>(x, sA, ln_in_g, ln_in_b, ln_s_g, ln_s_b,
                                     Wq, bq, Wk, bk, partials, nullptr, 0);
  k_update<<<B, blk, 0, stream>>>(partials, sA, ln_ff_g, ln_ff_b, Wv, bv,
                                  W_ih, b_ih, W_hh, b_hh, W1, b1, W2, b2,
                                  sB, 0, mfin, linv);
  // iteration 2 (store raw dots into attn region; slots -> d_out tail)
  k_flash<<<gridF, blk, 0, stream>>>(x, sB, ln_in_g, ln_in_b, ln_s_g, ln_s_b,
                                     Wq, bq, Wk, bk, partials, out, 1);
  k_update<<<B, blk, 0, stream>>>(partials, sB, ln_ff_g, ln_ff_b, Wv, bv,
                                  W_ih, b_ih, W_hh, b_hh, W1, b1, W2, b2,
                                  outslots, 1, mfin, linv);
  // normalize dots -> attn in place
  k_norm<<<1024, blk, 0, stream>>>(out, mfin, linv);
}